// Round 6
// baseline (191.835 us; speedup 1.0000x reference)
//
#include <hip/hip_runtime.h>

#define RES   256
#define RANK  12
#define NOUT  8
#define NPLANE (RES * RES)   // 65536 texels per plane

typedef float    f32x4 __attribute__((ext_vector_type(4)));
typedef unsigned u32x2 __attribute__((ext_vector_type(2)));

// Workspace layout: [0, 3MB) int8 planes Pq ; [3MB, 3MB+12) uint maxabs[3]
#define PQ_BYTES  ((size_t)3 * NPLANE * NOUT)          // 1,572,864 B... per plane 512KB *3 = 1.5MB
#define SLOT_OFF  PQ_BYTES

// ---------------------------------------------------------------------------
// Shared projection helper: thread tid (0..3*65536) -> 8 projected floats.
__device__ __forceinline__ void project_texel(
    int tid, const float* __restrict__ pxy, const float* __restrict__ pxz,
    const float* __restrict__ pyz, const float* __restrict__ w,
    int& p, float* __restrict__ o)
{
    p = tid >> 16;
    int t = tid & (NPLANE - 1);
    const float* plane = (p == 0) ? pxy : ((p == 1) ? pxz : pyz);
    const float4* src = (const float4*)(plane + (size_t)t * RANK);
    float4 a = src[0], b = src[1], c = src[2];
    float v[RANK] = {a.x, a.y, a.z, a.w, b.x, b.y, b.z, b.w, c.x, c.y, c.z, c.w};
#pragma unroll
    for (int k = 0; k < NOUT; ++k) {
        const float* wr = w + k * (3 * RANK) + p * RANK;
        float s = 0.0f;
#pragma unroll
        for (int r = 0; r < RANK; ++r) s = fmaf(wr[r], v[r], s);
        o[k] = s;
    }
}

// ---------------------------------------------------------------------------
// Kernel 1: projection + per-plane max|P| (atomicMax on float bit pattern —
// monotone for non-negative floats).
__global__ __launch_bounds__(256) void project_max_kernel(
    const float* __restrict__ pxy, const float* __restrict__ pxz,
    const float* __restrict__ pyz, const float* __restrict__ w,
    unsigned* __restrict__ slots)
{
    int tid = blockIdx.x * 256 + threadIdx.x;
    int p; float o[NOUT];
    project_texel(tid, pxy, pxz, pyz, w, p, o);
    float m = 0.0f;
#pragma unroll
    for (int k = 0; k < NOUT; ++k) m = fmaxf(m, fabsf(o[k]));
    // wave64 max-reduce
#pragma unroll
    for (int s = 1; s < 64; s <<= 1) m = fmaxf(m, __shfl_xor(m, s));
    if ((threadIdx.x & 63) == 0) atomicMax(slots + p, __float_as_uint(m));
}

// ---------------------------------------------------------------------------
// Kernel 2: re-project + quantize to biased int8 (q/127 scale per plane).
__global__ __launch_bounds__(256) void project_quant_kernel(
    const float* __restrict__ pxy, const float* __restrict__ pxz,
    const float* __restrict__ pyz, const float* __restrict__ w,
    const unsigned* __restrict__ slots, u32x2* __restrict__ Pq)
{
    int tid = blockIdx.x * 256 + threadIdx.x;
    int p; float o[NOUT];
    project_texel(tid, pxy, pxz, pyz, w, p, o);
    float mx = __uint_as_float(slots[p]);
    float inv = mx > 0.0f ? 127.0f / mx : 0.0f;
    unsigned q[NOUT];
#pragma unroll
    for (int k = 0; k < NOUT; ++k)
        q[k] = (unsigned)(__float2int_rn(o[k] * inv) + 128);   // [1,255]
    u32x2 d;
    d.x = q[0] | (q[1] << 8) | (q[2] << 16) | (q[3] << 24);
    d.y = q[4] | (q[5] << 8) | (q[6] << 16) | (q[7] << 24);
    Pq[tid] = d;
}

// ---------------------------------------------------------------------------
__device__ __forceinline__ float ub(unsigned v, int b)
{
    return (float)((v >> (8 * b)) & 0xffu);   // -> v_cvt_f32_ubyte<b>
}

__device__ __forceinline__ void unnorm(float c, int& i0, float& fr)
{
    float ic = fminf(fmaxf(fmaf(c, 128.0f, 127.5f), 0.0f), (float)(RES - 1));
    float f = floorf(ic);
    fr = ic - f;
    i0 = (int)f;
}

// ---------------------------------------------------------------------------
// Kernel 3: gather. 2 lanes per point, split by bilinear ROW. One 16-B load
// per (plane, row) covers both columns x0,x1 and all 8 int8 channels:
// 3 gather requests/lane = 6/point (vs 12 in the fp16 version — requests are
// the empirically limiting currency at ~0.6/cycle/CU).
__global__ __launch_bounds__(256) void triplane_gather_i8_kernel(
    const float* __restrict__ coords, const unsigned char* __restrict__ Pq,
    const unsigned* __restrict__ slots, const float* __restrict__ bias,
    float* __restrict__ out, int N)
{
    int g = blockIdx.x * 256 + threadIdx.x;
    int p = g >> 1;          // point index
    int r = g & 1;           // row side (0 = y0, 1 = y1)
    if (p >= N) return;

    float x = __builtin_nontemporal_load(coords + 3 * p + 0);
    float y = __builtin_nontemporal_load(coords + 3 * p + 1);
    float z = __builtin_nontemporal_load(coords + 3 * p + 2);

    int xi, yi, zi;
    float xf, yf, zf;
    unnorm(x, xi, xf);
    unnorm(y, yi, yf);
    unnorm(z, zi, zf);

    float sc0 = __uint_as_float(slots[0]) * (1.0f / 127.0f);
    float sc1 = __uint_as_float(slots[1]) * (1.0f / 127.0f);
    float sc2 = __uint_as_float(slots[2]) * (1.0f / 127.0f);

    float acc[NOUT];
#pragma unroll
    for (int k = 0; k < NOUT; ++k) acc[k] = 0.0f;
    float ksub = 0.0f;

    // per plane: (W-coord wi,wf) , (H-coord hi,hf), scale, plane byte offset
#pragma unroll
    for (int pl = 0; pl < 3; ++pl) {
        int   wi = (pl == 2) ? yi : xi;
        float wf = (pl == 2) ? yf : xf;
        int   hi = (pl == 0) ? yi : zi;
        float hf = (pl == 0) ? yf : zf;
        float sc = (pl == 0) ? sc0 : ((pl == 1) ? sc1 : sc2);

        int row = r ? min(hi + 1, RES - 1) : hi;
        float wr = r ? hf : (1.0f - hf);
        int b = min(wi, RES - 2);
        // wi == 255 edge: all weight on the hi texel (wf == 0 there)
        float lo_w = (wi <= RES - 2) ? (1.0f - wf) : 0.0f;
        float hi_w = (wi <= RES - 2) ? wf : 1.0f;
        float el = wr * lo_w * sc;
        float eh = wr * hi_w * sc;
        ksub += 128.0f * (el + eh);

        const uint4* addr = (const uint4*)(Pq + (size_t)pl * NPLANE * NOUT
                                              + ((size_t)row << 11) + ((size_t)b << 3));
        uint4 d = *addr;   // lo texel: d.x,d.y ; hi texel: d.z,d.w
#pragma unroll
        for (int c = 0; c < 4; ++c) {
            acc[c]     = fmaf(el, ub(d.x, c), fmaf(eh, ub(d.z, c), acc[c]));
            acc[c + 4] = fmaf(el, ub(d.y, c), fmaf(eh, ub(d.w, c), acc[c + 4]));
        }
    }
#pragma unroll
    for (int k = 0; k < NOUT; ++k) acc[k] -= ksub;

    // add partner lane (other row side)
#pragma unroll
    for (int k = 0; k < NOUT; ++k) acc[k] += __shfl_xor(acc[k], 1);

    // lane r stores channels 4r..4r+3
    const f32x4* b4 = (const f32x4*)bias;
    f32x4 bb = b4[r];
    f32x4 o;
    o.x = fminf(fmaxf((r ? acc[4] : acc[0]) + bb.x, -10.f), 10.f);
    o.y = fminf(fmaxf((r ? acc[5] : acc[1]) + bb.y, -10.f), 10.f);
    o.z = fminf(fmaxf((r ? acc[6] : acc[2]) + bb.z, -10.f), 10.f);
    o.w = fminf(fmaxf((r ? acc[7] : acc[3]) + bb.w, -10.f), 10.f);
    __builtin_nontemporal_store(o, (f32x4*)out + g);   // out[8p + 4r ...]
}

// ---------------------------------------------------------------------------
// Fallback (only if ws too small): direct fp32 sampling + 36x8 matvec.
__device__ __forceinline__ void sample12(const float* __restrict__ plane,
                                         float u, float v, float* __restrict__ f)
{
    float ix = fminf(fmaxf((u + 1.0f) * (RES * 0.5f) - 0.5f, 0.0f), RES - 1.0f);
    float iy = fminf(fmaxf((v + 1.0f) * (RES * 0.5f) - 0.5f, 0.0f), RES - 1.0f);
    float fx = floorf(ix), fy = floorf(iy);
    float wx = ix - fx, wy = iy - fy;
    int x0 = (int)fx, y0 = (int)fy;
    int x1 = min(x0 + 1, RES - 1), y1 = min(y0 + 1, RES - 1);
    float w00 = (1.0f - wx) * (1.0f - wy);
    float w01 = wx * (1.0f - wy);
    float w10 = (1.0f - wx) * wy;
    float w11 = wx * wy;
    const float4* p4 = (const float4*)plane;
    int i00 = (y0 * RES + x0) * 3, i01 = (y0 * RES + x1) * 3;
    int i10 = (y1 * RES + x0) * 3, i11 = (y1 * RES + x1) * 3;
#pragma unroll
    for (int j = 0; j < 3; ++j) {
        float4 c00 = p4[i00 + j], c01 = p4[i01 + j];
        float4 c10 = p4[i10 + j], c11 = p4[i11 + j];
        f[4 * j + 0] = fmaf(w00, c00.x, fmaf(w01, c01.x, fmaf(w10, c10.x, w11 * c11.x)));
        f[4 * j + 1] = fmaf(w00, c00.y, fmaf(w01, c01.y, fmaf(w10, c10.y, w11 * c11.y)));
        f[4 * j + 2] = fmaf(w00, c00.z, fmaf(w01, c01.z, fmaf(w10, c10.z, w11 * c11.z)));
        f[4 * j + 3] = fmaf(w00, c00.w, fmaf(w01, c01.w, fmaf(w10, c10.w, w11 * c11.w)));
    }
}

__global__ __launch_bounds__(256) void triplane_direct_kernel(
    const float* __restrict__ coords,
    const float* __restrict__ pxy, const float* __restrict__ pxz,
    const float* __restrict__ pyz,
    const float* __restrict__ w, const float* __restrict__ bias,
    float* __restrict__ out, int N)
{
    int i = blockIdx.x * 256 + threadIdx.x;
    if (i >= N) return;
    float x = coords[3 * i + 0];
    float y = coords[3 * i + 1];
    float z = coords[3 * i + 2];
    float f[3 * RANK];
    sample12(pxy, x, y, f + 0);
    sample12(pxz, x, z, f + RANK);
    sample12(pyz, y, z, f + 2 * RANK);
    float o[NOUT];
#pragma unroll
    for (int k = 0; k < NOUT; ++k) {
        const float* wr = w + k * (3 * RANK);
        float s = bias[k];
#pragma unroll
        for (int j = 0; j < 3 * RANK; ++j) s = fmaf(wr[j], f[j], s);
        o[k] = fminf(fmaxf(s, -10.f), 10.f);
    }
    float4* o4 = (float4*)(out + (size_t)i * NOUT);
    o4[0] = make_float4(o[0], o[1], o[2], o[3]);
    o4[1] = make_float4(o[4], o[5], o[6], o[7]);
}

// ---------------------------------------------------------------------------
extern "C" void kernel_launch(void* const* d_in, const int* in_sizes, int n_in,
                              void* d_out, int out_size, void* d_ws, size_t ws_size,
                              hipStream_t stream)
{
    const float* coords = (const float*)d_in[0];
    const float* pxy    = (const float*)d_in[1];
    const float* pxz    = (const float*)d_in[2];
    const float* pyz    = (const float*)d_in[3];
    const float* w      = (const float*)d_in[4];
    const float* b      = (const float*)d_in[5];
    float* out = (float*)d_out;
    int N = in_sizes[0] / 3;

    size_t need = PQ_BYTES + 12;
    if (ws_size >= need) {
        unsigned char* Pq = (unsigned char*)d_ws;
        unsigned* slots = (unsigned*)(Pq + SLOT_OFF);
        hipMemsetAsync(slots, 0, 12, stream);
        project_max_kernel<<<(3 * NPLANE) / 256, 256, 0, stream>>>(
            pxy, pxz, pyz, w, slots);
        project_quant_kernel<<<(3 * NPLANE) / 256, 256, 0, stream>>>(
            pxy, pxz, pyz, w, slots, (u32x2*)Pq);
        long long threads = 2LL * N;
        int blocks = (int)((threads + 255) / 256);
        triplane_gather_i8_kernel<<<blocks, 256, 0, stream>>>(
            coords, Pq, slots, b, out, N);
    } else {
        int blocks = (N + 255) / 256;
        triplane_direct_kernel<<<blocks, 256, 0, stream>>>(
            coords, pxy, pxz, pyz, w, b, out, N);
    }
}